// Round 3
// baseline (591.230 us; speedup 1.0000x reference)
//
#include <hip/hip_runtime.h>
#include <hip/hip_bf16.h>
#include <cstddef>
#include <cstdint>

#define FLT_MAX_C 3.402823466e+38f

typedef __attribute__((ext_vector_type(8))) __bf16 bf16x8;
typedef __attribute__((ext_vector_type(16))) float f32x16;

// Truncation-based fp32 -> bf16(hi) + bf16(lo) split, 8 elems -> two uint4.
// hi = trunc16(f); lo = trunc16(f - hi).  |err| <= 2^-16 rel per element.
__device__ __forceinline__ void split8(const float* v, uint4& hi, uint4& lo) {
    uint32_t hu[8], lu[8];
#pragma unroll
    for (int e = 0; e < 8; ++e) {
        union { float f; uint32_t u; } a, t, d;
        a.f = v[e];
        t.u = a.u & 0xffff0000u;
        d.f = a.f - t.f;
        hu[e] = t.u;
        lu[e] = d.u;
    }
    // pack hi16 of (even,odd) pairs: elem e -> ushort slot e
    hi.x = __builtin_amdgcn_perm(hu[1], hu[0], 0x07060302u);
    hi.y = __builtin_amdgcn_perm(hu[3], hu[2], 0x07060302u);
    hi.z = __builtin_amdgcn_perm(hu[5], hu[4], 0x07060302u);
    hi.w = __builtin_amdgcn_perm(hu[7], hu[6], 0x07060302u);
    lo.x = __builtin_amdgcn_perm(lu[1], lu[0], 0x07060302u);
    lo.y = __builtin_amdgcn_perm(lu[3], lu[2], 0x07060302u);
    lo.z = __builtin_amdgcn_perm(lu[5], lu[4], 0x07060302u);
    lo.w = __builtin_amdgcn_perm(lu[7], lu[6], 0x07060302u);
}

// ---------------------------------------------------------------------------
// Split-bf16 3-pass MFMA GEMM:  C[Ma,Na] = A[Ma,K] @ Bm[Na,K]^T (+bias)
// Block tile 64x128, BK=32, double-buffered LDS (48 KiB), ONE barrier/step.
// 256 thr = 4 waves (2x2), wave tile 32x64 (two 32x32x16 frags), 4 acc chains.
// 1D grid (bx*nby), by-inner + bijective XCD chunking for L2 B-panel reuse.
// Requires Ma % 64 == 0.
// ---------------------------------------------------------------------------
template<bool ADD_BIAS>
__global__ __launch_bounds__(256) void gemm_mfma_split(
    const float* __restrict__ A, const float* __restrict__ Bm,
    const float* __restrict__ bias, float* __restrict__ C,
    int Ma, int Na, int K)
{
    __shared__ alignas(16) unsigned short As_hi[2][2048];
    __shared__ alignas(16) unsigned short As_lo[2][2048];
    __shared__ alignas(16) unsigned short Bs_hi[2][4096];
    __shared__ alignas(16) unsigned short Bs_lo[2][4096];

    const int nby = Ma >> 6;
    // bijective XCD remap (m204): consecutive final wg share bx within an XCD
    const int nwg = gridDim.x;
    const int orig = blockIdx.x;
    const int qq = nwg >> 3, rr = nwg & 7;
    const int xcd = orig & 7, lin = orig >> 3;
    const int wg = ((xcd < rr) ? xcd * (qq + 1) : rr * (qq + 1) + (xcd - rr) * qq) + lin;
    const int by = wg % nby;
    const int bx = wg / nby;

    const int m0 = by * 64;
    const int n0 = bx * 128;

    const int tid  = threadIdx.x;
    const int lane = tid & 63;
    const int wid  = tid >> 6;
    const int wm   = wid >> 1;
    const int wn   = wid & 1;

    // staging: A row + 8-float seg; B row + 16-float seg
    const int ra = tid & 63, sa = tid >> 6;   // sa 0..3
    const int rb = tid >> 1, sb = tid & 1;    // rb 0..127

    const float* aB = A + (size_t)(m0 + ra) * K + sa * 8;
    const int gnb = n0 + rb;
    const float* bB = (gnb < Na) ? (Bm + (size_t)gnb * K + sb * 16) : nullptr;

    // LDS write offsets (ushort units); slot-XOR swizzle, same involution on read
    const int awOff  = ra * 32 + ((sa ^ (ra & 3)) << 3);
    const int bwOff0 = rb * 32 + (((sb * 2 + 0) ^ (rb & 3)) << 3);
    const int bwOff1 = rb * 32 + (((sb * 2 + 1) ^ (rb & 3)) << 3);

    // fragment read offsets
    const int lr = lane & 31, kh = lane >> 5;
    const int arow  = wm * 32 + lr;
    const int brow0 = wn * 64 + lr, brow1 = brow0 + 32;
    const int arOff0 = arow * 32 + ((kh ^ (arow & 3)) << 3);
    const int arOff1 = arow * 32 + (((2 + kh) ^ (arow & 3)) << 3);
    const int b0Off0 = brow0 * 32 + ((kh ^ (brow0 & 3)) << 3);
    const int b0Off1 = brow0 * 32 + (((2 + kh) ^ (brow0 & 3)) << 3);
    const int b1Off0 = brow1 * 32 + ((kh ^ (brow1 & 3)) << 3);
    const int b1Off1 = brow1 * 32 + (((2 + kh) ^ (brow1 & 3)) << 3);

    float ar_[8];
    float br_[16];
#pragma unroll
    for (int e = 0; e < 16; ++e) br_[e] = 0.0f;

    auto load_regs = [&](int s) {
        const int k0 = s << 5;
        if (k0 + sa * 8 + 8 <= K) {
            float4 v0 = *(const float4*)(aB + k0);
            float4 v1 = *(const float4*)(aB + k0 + 4);
            ar_[0]=v0.x; ar_[1]=v0.y; ar_[2]=v0.z; ar_[3]=v0.w;
            ar_[4]=v1.x; ar_[5]=v1.y; ar_[6]=v1.z; ar_[7]=v1.w;
        } else {
#pragma unroll
            for (int e = 0; e < 8; ++e) {
                const int k = k0 + sa * 8 + e;
                ar_[e] = (k < K) ? aB[k0 + e] : 0.0f;
            }
        }
        if (bB) {
            if (k0 + sb * 16 + 16 <= K) {
#pragma unroll
                for (int qd = 0; qd < 4; ++qd) {
                    float4 v = *(const float4*)(bB + k0 + qd * 4);
                    br_[qd*4+0]=v.x; br_[qd*4+1]=v.y;
                    br_[qd*4+2]=v.z; br_[qd*4+3]=v.w;
                }
            } else {
#pragma unroll
                for (int e = 0; e < 16; ++e) {
                    const int k = k0 + sb * 16 + e;
                    br_[e] = (k < K) ? bB[k0 + e] : 0.0f;
                }
            }
        }
    };

    auto write_tile = [&](int buf) {
        uint4 hi, lo;
        split8(ar_, hi, lo);
        *(uint4*)&As_hi[buf][awOff] = hi;
        *(uint4*)&As_lo[buf][awOff] = lo;
        split8(br_, hi, lo);
        *(uint4*)&Bs_hi[buf][bwOff0] = hi;
        *(uint4*)&Bs_lo[buf][bwOff0] = lo;
        split8(br_ + 8, hi, lo);
        *(uint4*)&Bs_hi[buf][bwOff1] = hi;
        *(uint4*)&Bs_lo[buf][bwOff1] = lo;
    };

    f32x16 acc00, acc01, acc10, acc11;
#pragma unroll
    for (int i = 0; i < 16; ++i) { acc00[i]=0.f; acc01[i]=0.f; acc10[i]=0.f; acc11[i]=0.f; }

    const int nsteps = (K + 31) >> 5;
    load_regs(0);
    write_tile(0);
    if (nsteps > 1) load_regs(1);
    __syncthreads();

    for (int s = 0; s < nsteps; ++s) {
        const int cur = s & 1;
        if (s + 1 < nsteps) write_tile(cur ^ 1);   // convert regs(s+1) into other buf
        if (s + 2 < nsteps) load_regs(s + 2);      // refill regs (in flight over MFMA)

        const unsigned short* Ah = As_hi[cur]; const unsigned short* Al = As_lo[cur];
        const unsigned short* Bh = Bs_hi[cur]; const unsigned short* Bl = Bs_lo[cur];
        bf16x8 a0h = *(const bf16x8*)&Ah[arOff0];
        bf16x8 a0l = *(const bf16x8*)&Al[arOff0];
        bf16x8 a1h = *(const bf16x8*)&Ah[arOff1];
        bf16x8 a1l = *(const bf16x8*)&Al[arOff1];
        bf16x8 p0h = *(const bf16x8*)&Bh[b0Off0];
        bf16x8 p0l = *(const bf16x8*)&Bl[b0Off0];
        bf16x8 q0h = *(const bf16x8*)&Bh[b1Off0];
        bf16x8 q0l = *(const bf16x8*)&Bl[b1Off0];
        bf16x8 p1h = *(const bf16x8*)&Bh[b0Off1];
        bf16x8 p1l = *(const bf16x8*)&Bl[b0Off1];
        bf16x8 q1h = *(const bf16x8*)&Bh[b1Off1];
        bf16x8 q1l = *(const bf16x8*)&Bl[b1Off1];

        acc00 = __builtin_amdgcn_mfma_f32_32x32x16_bf16(a0h, p0h, acc00, 0,0,0);
        acc01 = __builtin_amdgcn_mfma_f32_32x32x16_bf16(a0h, q0h, acc01, 0,0,0);
        acc10 = __builtin_amdgcn_mfma_f32_32x32x16_bf16(a1h, p1h, acc10, 0,0,0);
        acc11 = __builtin_amdgcn_mfma_f32_32x32x16_bf16(a1h, q1h, acc11, 0,0,0);
        acc00 = __builtin_amdgcn_mfma_f32_32x32x16_bf16(a0h, p0l, acc00, 0,0,0);
        acc01 = __builtin_amdgcn_mfma_f32_32x32x16_bf16(a0h, q0l, acc01, 0,0,0);
        acc10 = __builtin_amdgcn_mfma_f32_32x32x16_bf16(a1h, p1l, acc10, 0,0,0);
        acc11 = __builtin_amdgcn_mfma_f32_32x32x16_bf16(a1h, q1l, acc11, 0,0,0);
        acc00 = __builtin_amdgcn_mfma_f32_32x32x16_bf16(a0l, p0h, acc00, 0,0,0);
        acc01 = __builtin_amdgcn_mfma_f32_32x32x16_bf16(a0l, q0h, acc01, 0,0,0);
        acc10 = __builtin_amdgcn_mfma_f32_32x32x16_bf16(a1l, p1h, acc10, 0,0,0);
        acc11 = __builtin_amdgcn_mfma_f32_32x32x16_bf16(a1l, q1h, acc11, 0,0,0);
        __syncthreads();
    }

    f32x16 v0, v1;
#pragma unroll
    for (int i = 0; i < 16; ++i) { v0[i] = acc00[i] + acc10[i]; v1[i] = acc01[i] + acc11[i]; }

    // C/D layout: col=lane&31, row=(reg&3)+8*(reg>>2)+4*(lane>>5)
    const int col = lane & 31;
    const int rbase = 4 * kh;
#pragma unroll
    for (int r = 0; r < 16; ++r) {
        const int row = (r & 3) + 8 * (r >> 2) + rbase;
        const int gm = m0 + wm * 32 + row;
        int gn = n0 + wn * 64 + col;
        if (gn < Na) {
            float v = v0[r];
            if (ADD_BIAS) v += bias[gn];
            C[(size_t)gm * Na + gn] = v;
        }
        gn += 32;
        if (gn < Na) {
            float v = v1[r];
            if (ADD_BIAS) v += bias[gn];
            C[(size_t)gm * Na + gn] = v;
        }
    }
}

// ---------------------------------------------------------------------------
// Per-batch-row masking pipeline. One block (256 thr) per row.
// Top-50 selection now single-wave, register-resident (no barriers in loop).
// ---------------------------------------------------------------------------
__global__ __launch_bounds__(256) void rowproc_kernel(
    const float* __restrict__ zA,     // [B,1000]
    const float* __restrict__ sB,     // [B,6000]
    const float* __restrict__ phi,    // [B,6000]
    const float* __restrict__ psi,    // [B,6000]
    const float* __restrict__ decay,  // [6000]
    float* __restrict__ xbn, float* __restrict__ phin, float* __restrict__ psin,
    float* __restrict__ lam2)         // [B,1000]
{
    const int b = blockIdx.x;
    const int tid = threadIdx.x;
    const int lane = tid & 63;
    const int wid = tid >> 6;

    __shared__ float sig[6000];
    __shared__ float lam[1000];
    __shared__ int   wi[1000];
    __shared__ int   cw[1000];
    __shared__ float redf[4];

    const size_t rowTC = (size_t)b * 6000;
    const size_t rowM  = (size_t)b * 1000;

    // --- sigma + row min
    float lmin = FLT_MAX_C;
    for (int t = tid; t < 6000; t += 256) {
        float v = sB[rowTC + t] + zA[rowM + t / 6];
        sig[t] = v;
        lmin = fminf(lmin, v);
    }
#pragma unroll
    for (int off = 32; off > 0; off >>= 1)
        lmin = fminf(lmin, __shfl_down(lmin, off));
    if (lane == 0) redf[wid] = lmin;
    __syncthreads();
    if (tid == 0)
        redf[0] = fminf(fminf(redf[0], redf[1]), fminf(redf[2], redf[3]));
    __syncthreads();
    const float minv = redf[0];

    // --- per-column lam / winner cell; init cw
    for (int m = tid; m < 1000; m += 256) {
        float best = -FLT_MAX_C;
        int bj = 0;
#pragma unroll
        for (int j = 0; j < 6; ++j) {
            const int t = m * 6 + j;
            const float p = (1.0f - phi[rowTC + t]) * (sig[t] - minv);
            if (p > best) { best = p; bj = j; }
        }
        lam[m] = best;
        wi[m] = bj;
        cw[m] = 0;
    }
    __syncthreads();

    // --- top-50 of lam[1000]: wave 0 only, values in registers (ties -> low idx)
    if (wid == 0) {
        float lv[16];
        int wmask = 0;
#pragma unroll
        for (int j = 0; j < 16; ++j) {
            const int m = lane + (j << 6);
            lv[j] = (m < 1000) ? lam[m] : -FLT_MAX_C;
        }
        for (int it = 0; it < 50; ++it) {
            float bv = -FLT_MAX_C;
            int bi = 0x7fffffff;
#pragma unroll
            for (int j = 0; j < 16; ++j) {
                const int m = lane + (j << 6);
                const float v = lv[j];
                if (v > bv || (v == bv && m < bi)) { bv = v; bi = m; }
            }
#pragma unroll
            for (int off = 32; off > 0; off >>= 1) {
                const float ov = __shfl_xor(bv, off);
                const int oi  = __shfl_xor(bi, off);
                if (ov > bv || (ov == bv && oi < bi)) { bv = ov; bi = oi; }
            }
            if ((bi & 63) == lane) {
                const int jj = bi >> 6;
#pragma unroll
                for (int j = 0; j < 16; ++j)       // static indexing (no scratch)
                    if (j == jj) { lv[j] = -FLT_MAX_C; wmask |= (1 << j); }
            }
        }
#pragma unroll
        for (int j = 0; j < 16; ++j)
            if ((wmask >> j) & 1) cw[lane + (j << 6)] = 1;
    }
    __syncthreads();

    // --- write pass (per column), compute lam2
    for (int m = tid; m < 1000; m += 256) {
        const int won = cw[m];
        const int bj = wi[m];
        float cmax = -FLT_MAX_C;
        const size_t base = rowTC + (size_t)m * 6;
#pragma unroll
        for (int j = 0; j < 6; ++j) {
            const int t = m * 6 + j;
            const float y = (won && j == bj) ? tanhf(sig[t]) : 0.0f;
            const float pv = fmaxf(psi[base + j] * decay[t], y);
            const float fv = fmaxf(phi[base + j] * 0.5f, y);
            psin[base + j] = pv;
            xbn[base + j]  = pv;
            phin[base + j] = fv;
            cmax = fmaxf(cmax, pv);
        }
        lam2[rowM + m] = cmax;
    }
}

// ---------------------------------------------------------------------------
extern "C" void kernel_launch(void* const* d_in, const int* in_sizes, int n_in,
                              void* d_out, int out_size, void* d_ws, size_t ws_size,
                              hipStream_t stream)
{
    const float* x_a   = (const float*)d_in[0];  // [512,2048]
    const float* x_b   = (const float*)d_in[1];  // [512,6000]
    const float* phi   = (const float*)d_in[2];  // [512,6000]
    const float* psi   = (const float*)d_in[3];  // [512,6000]
    const float* W_a   = (const float*)d_in[4];  // [1000,2048]
    const float* W_b   = (const float*)d_in[5];  // [6000,6000]
    const float* W_d   = (const float*)d_in[6];  // [2048,1000]
    const float* b_d   = (const float*)d_in[7];  // [2048]
    const float* decay = (const float*)d_in[8];  // [6000]

    float* out  = (float*)d_out;                       // [512,2048]
    float* xbn  = out + (size_t)512 * 2048;            // [512,6000]
    float* phin = xbn + (size_t)512 * 6000;            // [512,6000]
    float* psin = phin + (size_t)512 * 6000;           // [512,6000]

    float* ws = (float*)d_ws;
    const size_t need = ((size_t)512 * 1000 * 2 + (size_t)512 * 6000) * sizeof(float);

    float* lam2 = ws;                    // [512,1000]
    float* z_a;                          // [512,1000]
    float* s_b;                          // [512,6000]
    if (ws_size >= need) {
        z_a = ws + 512 * 1000;
        s_b = ws + 2 * 512 * 1000;
    } else {
        z_a = out;       // consumed before final GEMM writes out
        s_b = psin;      // rowproc reads its s_b row into LDS before writing psin
    }

    dim3 blk(256);
    // z_a = x_a @ W_a^T          [512,1000], K=2048; grid = ceil(1000/128)*8
    gemm_mfma_split<false><<<dim3(8 * 8), blk, 0, stream>>>(x_a, W_a, nullptr, z_a, 512, 1000, 2048);
    // s_b = x_b @ W_b^T          [512,6000], K=6000; grid = 47*8
    gemm_mfma_split<false><<<dim3(47 * 8), blk, 0, stream>>>(x_b, W_b, nullptr, s_b, 512, 6000, 6000);
    // masking pipeline
    rowproc_kernel<<<512, blk, 0, stream>>>(z_a, s_b, phi, psi, decay, xbn, phin, psin, lam2);
    // out = lam2 @ W_d^T + b_d   [512,2048], K=1000; grid = 16*8
    gemm_mfma_split<true><<<dim3(16 * 8), blk, 0, stream>>>(lam2, W_d, b_d, out, 512, 2048, 1000);
}

// Round 4
// 475.682 us; speedup vs baseline: 1.2429x; 1.2429x over previous
//
#include <hip/hip_runtime.h>
#include <hip/hip_bf16.h>
#include <cstddef>
#include <cstdint>

#define FLT_MAX_C 3.402823466e+38f

typedef __attribute__((ext_vector_type(8))) __bf16 bf16x8;
typedef __attribute__((ext_vector_type(16))) float f32x16;

// Truncation-based fp32 -> bf16(hi) + bf16(lo) split, 8 elems -> two uint4.
// hi = trunc16(f); lo = trunc16(f - hi).  |err| <= 2^-16 rel per element.
__device__ __forceinline__ void split8(const float* v, uint4& hi, uint4& lo) {
    uint32_t hu[8], lu[8];
#pragma unroll
    for (int e = 0; e < 8; ++e) {
        union { float f; uint32_t u; } a, t, d;
        a.f = v[e];
        t.u = a.u & 0xffff0000u;
        d.f = a.f - t.f;
        hu[e] = t.u;
        lu[e] = d.u;
    }
    hi.x = __builtin_amdgcn_perm(hu[1], hu[0], 0x07060302u);
    hi.y = __builtin_amdgcn_perm(hu[3], hu[2], 0x07060302u);
    hi.z = __builtin_amdgcn_perm(hu[5], hu[4], 0x07060302u);
    hi.w = __builtin_amdgcn_perm(hu[7], hu[6], 0x07060302u);
    lo.x = __builtin_amdgcn_perm(lu[1], lu[0], 0x07060302u);
    lo.y = __builtin_amdgcn_perm(lu[3], lu[2], 0x07060302u);
    lo.z = __builtin_amdgcn_perm(lu[5], lu[4], 0x07060302u);
    lo.w = __builtin_amdgcn_perm(lu[7], lu[6], 0x07060302u);
}

// ---------------------------------------------------------------------------
// Split-bf16 3-pass MFMA GEMM:  C[Ma,Na] = A[Ma,K] @ Bm[Na,K]^T (+bias)
// Block tile 64x64, BK=32, double-buffered LDS (32 KiB), ONE barrier/step.
// 256 thr = 4 waves (2x2), wave tile 32x32 (one 32x32x16 output), 2 acc chains.
// LDS is FRAGMENT-MAJOR [k-slot][row][8 bf16]: half-wave reads are 512
// contiguous bytes -> conflict-free; staging writes are 1 KiB/wave contiguous
// -> conflict-free. No swizzle.
// 1D grid, by-inner + bijective XCD chunking for L2 B-panel reuse.
// Requires Ma % 64 == 0.
// ---------------------------------------------------------------------------
template<bool ADD_BIAS>
__global__ __launch_bounds__(256) void gemm_mfma_split(
    const float* __restrict__ A, const float* __restrict__ Bm,
    const float* __restrict__ bias, float* __restrict__ C,
    int Ma, int Na, int K)
{
    // [buf][(slot*64 + row)*8]  slot=k/8 (0..3), row=tile row (0..63)
    __shared__ alignas(16) unsigned short As_hi[2][2048];
    __shared__ alignas(16) unsigned short As_lo[2][2048];
    __shared__ alignas(16) unsigned short Bs_hi[2][2048];
    __shared__ alignas(16) unsigned short Bs_lo[2][2048];

    const int nby = Ma >> 6;
    // bijective XCD remap (m204): consecutive final wg share bx within an XCD
    const int nwg = gridDim.x;
    const int orig = blockIdx.x;
    const int qq = nwg >> 3, rr = nwg & 7;
    const int xcd = orig & 7, lin = orig >> 3;
    const int wg = ((xcd < rr) ? xcd * (qq + 1) : rr * (qq + 1) + (xcd - rr) * qq) + lin;
    const int by = wg % nby;
    const int bx = wg / nby;

    const int m0 = by * 64;
    const int n0 = bx * 64;

    const int tid  = threadIdx.x;
    const int lane = tid & 63;
    const int wid  = tid >> 6;
    const int wm   = wid >> 1;
    const int wn   = wid & 1;

    // staging: thread -> (row ra, k-slot sa); stages 8 floats of A and of B
    const int ra = tid & 63, sa = tid >> 6;

    const float* aB = A + (size_t)(m0 + ra) * K + sa * 8;
    const int gnb = n0 + ra;
    const float* bB = (gnb < Na) ? (Bm + (size_t)gnb * K + sa * 8) : nullptr;

    const int wOff = (sa * 64 + ra) * 8;   // ushort units; wave-contiguous 1 KiB

    // fragment read offsets (conflict-free: half-wave = 512 contiguous bytes)
    const int lr = lane & 31, kh = lane >> 5;
    const int arow = wm * 32 + lr;
    const int brow = wn * 32 + lr;
    const int aOff0 = ((kh)     * 64 + arow) * 8;
    const int aOff1 = ((2 + kh) * 64 + arow) * 8;
    const int bOff0 = ((kh)     * 64 + brow) * 8;
    const int bOff1 = ((2 + kh) * 64 + brow) * 8;

    float ar_[8];
    float br_[8];
#pragma unroll
    for (int e = 0; e < 8; ++e) br_[e] = 0.0f;

    auto load_regs = [&](int s) {
        const int k0 = s << 5;
        const int ka = k0 + sa * 8;
        if (ka + 8 <= K) {
            float4 v0 = *(const float4*)(aB + k0);
            float4 v1 = *(const float4*)(aB + k0 + 4);
            ar_[0]=v0.x; ar_[1]=v0.y; ar_[2]=v0.z; ar_[3]=v0.w;
            ar_[4]=v1.x; ar_[5]=v1.y; ar_[6]=v1.z; ar_[7]=v1.w;
            if (bB) {
                float4 w0 = *(const float4*)(bB + k0);
                float4 w1 = *(const float4*)(bB + k0 + 4);
                br_[0]=w0.x; br_[1]=w0.y; br_[2]=w0.z; br_[3]=w0.w;
                br_[4]=w1.x; br_[5]=w1.y; br_[6]=w1.z; br_[7]=w1.w;
            }
        } else {
#pragma unroll
            for (int e = 0; e < 8; ++e)
                ar_[e] = (ka + e < K) ? aB[k0 + e] : 0.0f;
            if (bB) {
#pragma unroll
                for (int e = 0; e < 8; ++e)
                    br_[e] = (ka + e < K) ? bB[k0 + e] : 0.0f;
            }
        }
    };

    auto write_tile = [&](int buf) {
        uint4 hi, lo;
        split8(ar_, hi, lo);
        *(uint4*)&As_hi[buf][wOff] = hi;
        *(uint4*)&As_lo[buf][wOff] = lo;
        split8(br_, hi, lo);
        *(uint4*)&Bs_hi[buf][wOff] = hi;
        *(uint4*)&Bs_lo[buf][wOff] = lo;
    };

    f32x16 accA, accB;
#pragma unroll
    for (int i = 0; i < 16; ++i) { accA[i] = 0.0f; accB[i] = 0.0f; }

    const int nsteps = (K + 31) >> 5;
    load_regs(0);
    write_tile(0);
    if (nsteps > 1) load_regs(1);
    __syncthreads();

    for (int s = 0; s < nsteps; ++s) {
        const int cur = s & 1;
        if (s + 1 < nsteps) write_tile(cur ^ 1);   // convert regs(s+1) -> other buf
        if (s + 2 < nsteps) load_regs(s + 2);      // refill regs (in flight over MFMA)

        bf16x8 a0h = *(const bf16x8*)&As_hi[cur][aOff0];
        bf16x8 a0l = *(const bf16x8*)&As_lo[cur][aOff0];
        bf16x8 a1h = *(const bf16x8*)&As_hi[cur][aOff1];
        bf16x8 a1l = *(const bf16x8*)&As_lo[cur][aOff1];
        bf16x8 b0h = *(const bf16x8*)&Bs_hi[cur][bOff0];
        bf16x8 b0l = *(const bf16x8*)&Bs_lo[cur][bOff0];
        bf16x8 b1h = *(const bf16x8*)&Bs_hi[cur][bOff1];
        bf16x8 b1l = *(const bf16x8*)&Bs_lo[cur][bOff1];

        // two independent chains (k 0-15 -> accA, k 16-31 -> accB), interleaved
        accA = __builtin_amdgcn_mfma_f32_32x32x16_bf16(a0h, b0h, accA, 0,0,0);
        accB = __builtin_amdgcn_mfma_f32_32x32x16_bf16(a1h, b1h, accB, 0,0,0);
        accA = __builtin_amdgcn_mfma_f32_32x32x16_bf16(a0h, b0l, accA, 0,0,0);
        accB = __builtin_amdgcn_mfma_f32_32x32x16_bf16(a1h, b1l, accB, 0,0,0);
        accA = __builtin_amdgcn_mfma_f32_32x32x16_bf16(a0l, b0h, accA, 0,0,0);
        accB = __builtin_amdgcn_mfma_f32_32x32x16_bf16(a1l, b1h, accB, 0,0,0);
        __syncthreads();
    }

    f32x16 acc;
#pragma unroll
    for (int i = 0; i < 16; ++i) acc[i] = accA[i] + accB[i];

    // C/D layout: col=lane&31, row=(reg&3)+8*(reg>>2)+4*(lane>>5)
    const int col = lane & 31;
    const int rbase = 4 * kh;
#pragma unroll
    for (int r = 0; r < 16; ++r) {
        const int row = (r & 3) + 8 * (r >> 2) + rbase;
        const int gm = m0 + wm * 32 + row;       // Ma % 64 == 0 -> valid
        const int gn = n0 + wn * 32 + col;
        if (gn < Na) {
            float v = acc[r];
            if (ADD_BIAS) v += bias[gn];
            C[(size_t)gm * Na + gn] = v;
        }
    }
}

// ---------------------------------------------------------------------------
// Per-batch-row masking pipeline. One block (256 thr) per row.
// Top-50 selection single-wave, register-resident.
// ---------------------------------------------------------------------------
__global__ __launch_bounds__(256) void rowproc_kernel(
    const float* __restrict__ zA,     // [B,1000]
    const float* __restrict__ sB,     // [B,6000]
    const float* __restrict__ phi,    // [B,6000]
    const float* __restrict__ psi,    // [B,6000]
    const float* __restrict__ decay,  // [6000]
    float* __restrict__ xbn, float* __restrict__ phin, float* __restrict__ psin,
    float* __restrict__ lam2)         // [B,1000]
{
    const int b = blockIdx.x;
    const int tid = threadIdx.x;
    const int lane = tid & 63;
    const int wid = tid >> 6;

    __shared__ float sig[6000];
    __shared__ float lam[1000];
    __shared__ int   wi[1000];
    __shared__ int   cw[1000];
    __shared__ float redf[4];

    const size_t rowTC = (size_t)b * 6000;
    const size_t rowM  = (size_t)b * 1000;

    // --- sigma + row min
    float lmin = FLT_MAX_C;
    for (int t = tid; t < 6000; t += 256) {
        float v = sB[rowTC + t] + zA[rowM + t / 6];
        sig[t] = v;
        lmin = fminf(lmin, v);
    }
#pragma unroll
    for (int off = 32; off > 0; off >>= 1)
        lmin = fminf(lmin, __shfl_down(lmin, off));
    if (lane == 0) redf[wid] = lmin;
    __syncthreads();
    if (tid == 0)
        redf[0] = fminf(fminf(redf[0], redf[1]), fminf(redf[2], redf[3]));
    __syncthreads();
    const float minv = redf[0];

    // --- per-column lam / winner cell; init cw
    for (int m = tid; m < 1000; m += 256) {
        float best = -FLT_MAX_C;
        int bj = 0;
#pragma unroll
        for (int j = 0; j < 6; ++j) {
            const int t = m * 6 + j;
            const float p = (1.0f - phi[rowTC + t]) * (sig[t] - minv);
            if (p > best) { best = p; bj = j; }
        }
        lam[m] = best;
        wi[m] = bj;
        cw[m] = 0;
    }
    __syncthreads();

    // --- top-50 of lam[1000]: wave 0 only, register-resident (ties -> low idx)
    if (wid == 0) {
        float lv[16];
        int wmask = 0;
#pragma unroll
        for (int j = 0; j < 16; ++j) {
            const int m = lane + (j << 6);
            lv[j] = (m < 1000) ? lam[m] : -FLT_MAX_C;
        }
        for (int it = 0; it < 50; ++it) {
            float bv = -FLT_MAX_C;
            int bi = 0x7fffffff;
#pragma unroll
            for (int j = 0; j < 16; ++j) {
                const int m = lane + (j << 6);
                const float v = lv[j];
                if (v > bv || (v == bv && m < bi)) { bv = v; bi = m; }
            }
#pragma unroll
            for (int off = 32; off > 0; off >>= 1) {
                const float ov = __shfl_xor(bv, off);
                const int oi  = __shfl_xor(bi, off);
                if (ov > bv || (ov == bv && oi < bi)) { bv = ov; bi = oi; }
            }
            if ((bi & 63) == lane) {
                const int jj = bi >> 6;
#pragma unroll
                for (int j = 0; j < 16; ++j)       // static indexing (no scratch)
                    if (j == jj) { lv[j] = -FLT_MAX_C; wmask |= (1 << j); }
            }
        }
#pragma unroll
        for (int j = 0; j < 16; ++j)
            if ((wmask >> j) & 1) cw[lane + (j << 6)] = 1;
    }
    __syncthreads();

    // --- write pass (per column), compute lam2
    for (int m = tid; m < 1000; m += 256) {
        const int won = cw[m];
        const int bj = wi[m];
        float cmax = -FLT_MAX_C;
        const size_t base = rowTC + (size_t)m * 6;
#pragma unroll
        for (int j = 0; j < 6; ++j) {
            const int t = m * 6 + j;
            const float y = (won && j == bj) ? tanhf(sig[t]) : 0.0f;
            const float pv = fmaxf(psi[base + j] * decay[t], y);
            const float fv = fmaxf(phi[base + j] * 0.5f, y);
            psin[base + j] = pv;
            xbn[base + j]  = pv;
            phin[base + j] = fv;
            cmax = fmaxf(cmax, pv);
        }
        lam2[rowM + m] = cmax;
    }
}

// ---------------------------------------------------------------------------
extern "C" void kernel_launch(void* const* d_in, const int* in_sizes, int n_in,
                              void* d_out, int out_size, void* d_ws, size_t ws_size,
                              hipStream_t stream)
{
    const float* x_a   = (const float*)d_in[0];  // [512,2048]
    const float* x_b   = (const float*)d_in[1];  // [512,6000]
    const float* phi   = (const float*)d_in[2];  // [512,6000]
    const float* psi   = (const float*)d_in[3];  // [512,6000]
    const float* W_a   = (const float*)d_in[4];  // [1000,2048]
    const float* W_b   = (const float*)d_in[5];  // [6000,6000]
    const float* W_d   = (const float*)d_in[6];  // [2048,1000]
    const float* b_d   = (const float*)d_in[7];  // [2048]
    const float* decay = (const float*)d_in[8];  // [6000]

    float* out  = (float*)d_out;                       // [512,2048]
    float* xbn  = out + (size_t)512 * 2048;            // [512,6000]
    float* phin = xbn + (size_t)512 * 6000;            // [512,6000]
    float* psin = phin + (size_t)512 * 6000;           // [512,6000]

    float* ws = (float*)d_ws;
    const size_t need = ((size_t)512 * 1000 * 2 + (size_t)512 * 6000) * sizeof(float);

    float* lam2 = ws;                    // [512,1000]
    float* z_a;                          // [512,1000]
    float* s_b;                          // [512,6000]
    if (ws_size >= need) {
        z_a = ws + 512 * 1000;
        s_b = ws + 2 * 512 * 1000;
    } else {
        z_a = out;       // consumed before final GEMM writes out
        s_b = psin;      // rowproc reads its s_b row into LDS before writing psin
    }

    dim3 blk(256);
    // z_a = x_a @ W_a^T          [512,1000], K=2048; grid = 16 bx * 8 by
    gemm_mfma_split<false><<<dim3(16 * 8), blk, 0, stream>>>(x_a, W_a, nullptr, z_a, 512, 1000, 2048);
    // s_b = x_b @ W_b^T          [512,6000], K=6000; grid = 94 bx * 8 by
    gemm_mfma_split<false><<<dim3(94 * 8), blk, 0, stream>>>(x_b, W_b, nullptr, s_b, 512, 6000, 6000);
    // masking pipeline
    rowproc_kernel<<<512, blk, 0, stream>>>(z_a, s_b, phi, psi, decay, xbn, phin, psin, lam2);
    // out = lam2 @ W_d^T + b_d   [512,2048], K=1000; grid = 32 bx * 8 by
    gemm_mfma_split<true><<<dim3(32 * 8), blk, 0, stream>>>(lam2, W_d, b_d, out, 512, 2048, 1000);
}

// Round 9
// 463.979 us; speedup vs baseline: 1.2743x; 1.0252x over previous
//
#include <hip/hip_runtime.h>
#include <hip/hip_bf16.h>
#include <cstddef>
#include <cstdint>

#define FLT_MAX_C 3.402823466e+38f

typedef __attribute__((ext_vector_type(8))) __bf16 bf16x8;
typedef __attribute__((ext_vector_type(16))) float f32x16;

// Truncation-based fp32 -> bf16(hi) + bf16(lo) split, 8 elems -> two uint4.
// IDENTICAL to round 4 (bit-exact reproduction of the passing configuration).
__device__ __forceinline__ void split8(const float* v, uint4& hi, uint4& lo) {
    uint32_t hu[8], lu[8];
#pragma unroll
    for (int e = 0; e < 8; ++e) {
        union { float f; uint32_t u; } a, t, d;
        a.f = v[e];
        t.u = a.u & 0xffff0000u;
        d.f = a.f - t.f;
        hu[e] = t.u;
        lu[e] = d.u;
    }
    hi.x = __builtin_amdgcn_perm(hu[1], hu[0], 0x07060302u);
    hi.y = __builtin_amdgcn_perm(hu[3], hu[2], 0x07060302u);
    hi.z = __builtin_amdgcn_perm(hu[5], hu[4], 0x07060302u);
    hi.w = __builtin_amdgcn_perm(hu[7], hu[6], 0x07060302u);
    lo.x = __builtin_amdgcn_perm(lu[1], lu[0], 0x07060302u);
    lo.y = __builtin_amdgcn_perm(lu[3], lu[2], 0x07060302u);
    lo.z = __builtin_amdgcn_perm(lu[5], lu[4], 0x07060302u);
    lo.w = __builtin_amdgcn_perm(lu[7], lu[6], 0x07060302u);
}

// ---------------------------------------------------------------------------
// Split-bf16 3-pass MFMA GEMM — arithmetic bit-identical to round 4 (passed).
// Step-loop ORDER MATTERS (round-8 bug): write_tile(cur^1) consumes ar_/br_
// (tile s+1, loaded last iteration) and MUST precede load_regs(s+2), which
// overwrites those registers with tile s+2.
// Scheduling deltas vs round 4 (value-preserving only):
//   - fragment ds_reads issue first after the barrier (they gate MFMA)
//   - s_setprio(1) around the MFMA cluster
// Block tile 64x64, BK=32, double-buffered LDS (32 KiB), ONE barrier/step.
// Fragment-major LDS [k-slot][row][8 bf16]: conflict-free reads & writes.
// 1D grid, by-inner + bijective XCD chunking. Requires Ma % 64 == 0.
// ---------------------------------------------------------------------------
template<bool ADD_BIAS>
__global__ __launch_bounds__(256) void gemm_mfma_split(
    const float* __restrict__ A, const float* __restrict__ Bm,
    const float* __restrict__ bias, float* __restrict__ C,
    int Ma, int Na, int K)
{
    __shared__ alignas(16) unsigned short As_hi[2][2048];
    __shared__ alignas(16) unsigned short As_lo[2][2048];
    __shared__ alignas(16) unsigned short Bs_hi[2][2048];
    __shared__ alignas(16) unsigned short Bs_lo[2][2048];

    const int nby = Ma >> 6;
    // bijective XCD remap (m204)
    const int nwg = gridDim.x;
    const int orig = blockIdx.x;
    const int qq = nwg >> 3, rr = nwg & 7;
    const int xcd = orig & 7, lin = orig >> 3;
    const int wg = ((xcd < rr) ? xcd * (qq + 1) : rr * (qq + 1) + (xcd - rr) * qq) + lin;
    const int by = wg % nby;
    const int bx = wg / nby;

    const int m0 = by * 64;
    const int n0 = bx * 64;

    const int tid  = threadIdx.x;
    const int lane = tid & 63;
    const int wid  = tid >> 6;
    const int wm   = wid >> 1;
    const int wn   = wid & 1;

    // staging: thread -> (row ra, k-slot sa); stages 8 floats of A and of B
    const int ra = tid & 63, sa = tid >> 6;

    const float* aB = A + (size_t)(m0 + ra) * K + sa * 8;
    const int gnb = n0 + ra;
    const float* bB = (gnb < Na) ? (Bm + (size_t)gnb * K + sa * 8) : nullptr;

    const int wOff = (sa * 64 + ra) * 8;   // ushort units; wave-contiguous 1 KiB

    // fragment read offsets (half-wave = 512 contiguous bytes, conflict-free)
    const int lr = lane & 31, kh = lane >> 5;
    const int arow = wm * 32 + lr;
    const int brow = wn * 32 + lr;
    const int aOff0 = ((kh)     * 64 + arow) * 8;
    const int aOff1 = ((2 + kh) * 64 + arow) * 8;
    const int bOff0 = ((kh)     * 64 + brow) * 8;
    const int bOff1 = ((2 + kh) * 64 + brow) * 8;

    float ar_[8];
    float br_[8];
#pragma unroll
    for (int e = 0; e < 8; ++e) br_[e] = 0.0f;

    auto load_regs = [&](int s) {
        const int k0 = s << 5;
        const int ka = k0 + sa * 8;
        if (ka + 8 <= K) {
            float4 v0 = *(const float4*)(aB + k0);
            float4 v1 = *(const float4*)(aB + k0 + 4);
            ar_[0]=v0.x; ar_[1]=v0.y; ar_[2]=v0.z; ar_[3]=v0.w;
            ar_[4]=v1.x; ar_[5]=v1.y; ar_[6]=v1.z; ar_[7]=v1.w;
            if (bB) {
                float4 w0 = *(const float4*)(bB + k0);
                float4 w1 = *(const float4*)(bB + k0 + 4);
                br_[0]=w0.x; br_[1]=w0.y; br_[2]=w0.z; br_[3]=w0.w;
                br_[4]=w1.x; br_[5]=w1.y; br_[6]=w1.z; br_[7]=w1.w;
            }
        } else {
#pragma unroll
            for (int e = 0; e < 8; ++e)
                ar_[e] = (ka + e < K) ? aB[k0 + e] : 0.0f;
            if (bB) {
#pragma unroll
                for (int e = 0; e < 8; ++e)
                    br_[e] = (ka + e < K) ? bB[k0 + e] : 0.0f;
            }
        }
    };

    auto write_tile = [&](int buf) {
        uint4 hi, lo;
        split8(ar_, hi, lo);
        *(uint4*)&As_hi[buf][wOff] = hi;
        *(uint4*)&As_lo[buf][wOff] = lo;
        split8(br_, hi, lo);
        *(uint4*)&Bs_hi[buf][wOff] = hi;
        *(uint4*)&Bs_lo[buf][wOff] = lo;
    };

    f32x16 accA, accB;
#pragma unroll
    for (int i = 0; i < 16; ++i) { accA[i] = 0.0f; accB[i] = 0.0f; }

    const int nsteps = (K + 31) >> 5;
    load_regs(0);
    write_tile(0);
    if (nsteps > 1) load_regs(1);
    __syncthreads();

    for (int s = 0; s < nsteps; ++s) {
        const int cur = s & 1;

        // 1) fragment reads first — depend only on the previous barrier;
        //    they touch buf[cur], disjoint from the staging writes below.
        bf16x8 a0h = *(const bf16x8*)&As_hi[cur][aOff0];
        bf16x8 a0l = *(const bf16x8*)&As_lo[cur][aOff0];
        bf16x8 a1h = *(const bf16x8*)&As_hi[cur][aOff1];
        bf16x8 a1l = *(const bf16x8*)&As_lo[cur][aOff1];
        bf16x8 b0h = *(const bf16x8*)&Bs_hi[cur][bOff0];
        bf16x8 b0l = *(const bf16x8*)&Bs_lo[cur][bOff0];
        bf16x8 b1h = *(const bf16x8*)&Bs_hi[cur][bOff1];
        bf16x8 b1l = *(const bf16x8*)&Bs_lo[cur][bOff1];

        // 2) write_tile BEFORE load_regs: ar_/br_ hold tile s+1 now;
        //    load_regs(s+2) would clobber them (round-8 bug).
        if (s + 1 < nsteps) write_tile(cur ^ 1);
        if (s + 2 < nsteps) load_regs(s + 2);

        // 3) MFMA: exact round-4 sequence (bit-identical accumulation)
        __builtin_amdgcn_s_setprio(1);
        accA = __builtin_amdgcn_mfma_f32_32x32x16_bf16(a0h, b0h, accA, 0,0,0);
        accB = __builtin_amdgcn_mfma_f32_32x32x16_bf16(a1h, b1h, accB, 0,0,0);
        accA = __builtin_amdgcn_mfma_f32_32x32x16_bf16(a0h, b0l, accA, 0,0,0);
        accB = __builtin_amdgcn_mfma_f32_32x32x16_bf16(a1h, b1l, accB, 0,0,0);
        accA = __builtin_amdgcn_mfma_f32_32x32x16_bf16(a0l, b0h, accA, 0,0,0);
        accB = __builtin_amdgcn_mfma_f32_32x32x16_bf16(a1l, b1h, accB, 0,0,0);
        __builtin_amdgcn_s_setprio(0);
        __syncthreads();
    }

    f32x16 acc;
#pragma unroll
    for (int i = 0; i < 16; ++i) acc[i] = accA[i] + accB[i];

    // C/D layout: col=lane&31, row=(reg&3)+8*(reg>>2)+4*(lane>>5)
    const int col = lane & 31;
    const int rbase = 4 * kh;
#pragma unroll
    for (int r = 0; r < 16; ++r) {
        const int row = (r & 3) + 8 * (r >> 2) + rbase;
        const int gm = m0 + wm * 32 + row;       // Ma % 64 == 0 -> valid
        const int gn = n0 + wn * 32 + col;
        if (gn < Na) {
            float v = acc[r];
            if (ADD_BIAS) v += bias[gn];
            C[(size_t)gm * Na + gn] = v;
        }
    }
}

// ---------------------------------------------------------------------------
// Per-batch-row masking pipeline — IDENTICAL to round 4 (passed).
// sB aliases the xbn region: each block stages its sB row into LDS before
// the barrier-ordered overwrite of the same row -> safe; no restrict on it.
// ---------------------------------------------------------------------------
__global__ __launch_bounds__(256) void rowproc_kernel(
    const float* __restrict__ zA,     // [B,1000]
    const float* sB,                  // [B,6000] (aliases xbn region)
    const float* __restrict__ phi,    // [B,6000]
    const float* __restrict__ psi,    // [B,6000]
    const float* __restrict__ decay,  // [6000]
    float* xbn, float* __restrict__ phin, float* __restrict__ psin,
    float* __restrict__ lam2)         // [B,1000]
{
    const int b = blockIdx.x;
    const int tid = threadIdx.x;
    const int lane = tid & 63;
    const int wid = tid >> 6;

    __shared__ float sig[6000];
    __shared__ float lam[1000];
    __shared__ int   wi[1000];
    __shared__ int   cw[1000];
    __shared__ float redf[4];

    const size_t rowTC = (size_t)b * 6000;
    const size_t rowM  = (size_t)b * 1000;

    // --- sigma + row min (round-4 arithmetic: sB + zA, single buffers)
    float lmin = FLT_MAX_C;
    for (int t = tid; t < 6000; t += 256) {
        float v = sB[rowTC + t] + zA[rowM + t / 6];
        sig[t] = v;
        lmin = fminf(lmin, v);
    }
#pragma unroll
    for (int off = 32; off > 0; off >>= 1)
        lmin = fminf(lmin, __shfl_down(lmin, off));
    if (lane == 0) redf[wid] = lmin;
    __syncthreads();
    if (tid == 0)
        redf[0] = fminf(fminf(redf[0], redf[1]), fminf(redf[2], redf[3]));
    __syncthreads();
    const float minv = redf[0];

    // --- per-column lam / winner cell; init cw
    for (int m = tid; m < 1000; m += 256) {
        float best = -FLT_MAX_C;
        int bj = 0;
#pragma unroll
        for (int j = 0; j < 6; ++j) {
            const int t = m * 6 + j;
            const float p = (1.0f - phi[rowTC + t]) * (sig[t] - minv);
            if (p > best) { best = p; bj = j; }
        }
        lam[m] = best;
        wi[m] = bj;
        cw[m] = 0;
    }
    __syncthreads();

    // --- top-50 of lam[1000]: wave 0 only, register-resident (ties -> low idx)
    if (wid == 0) {
        float lv[16];
        int wmask = 0;
#pragma unroll
        for (int j = 0; j < 16; ++j) {
            const int m = lane + (j << 6);
            lv[j] = (m < 1000) ? lam[m] : -FLT_MAX_C;
        }
        for (int it = 0; it < 50; ++it) {
            float bv = -FLT_MAX_C;
            int bi = 0x7fffffff;
#pragma unroll
            for (int j = 0; j < 16; ++j) {
                const int m = lane + (j << 6);
                const float v = lv[j];
                if (v > bv || (v == bv && m < bi)) { bv = v; bi = m; }
            }
#pragma unroll
            for (int off = 32; off > 0; off >>= 1) {
                const float ov = __shfl_xor(bv, off);
                const int oi  = __shfl_xor(bi, off);
                if (ov > bv || (ov == bv && oi < bi)) { bv = ov; bi = oi; }
            }
            if ((bi & 63) == lane) {
                const int jj = bi >> 6;
#pragma unroll
                for (int j = 0; j < 16; ++j)       // static indexing
                    if (j == jj) { lv[j] = -FLT_MAX_C; wmask |= (1 << j); }
            }
        }
#pragma unroll
        for (int j = 0; j < 16; ++j)
            if ((wmask >> j) & 1) cw[lane + (j << 6)] = 1;
    }
    __syncthreads();

    // --- write pass (per column), compute lam2
    for (int m = tid; m < 1000; m += 256) {
        const int won = cw[m];
        const int bj = wi[m];
        float cmax = -FLT_MAX_C;
        const size_t base = rowTC + (size_t)m * 6;
#pragma unroll
        for (int j = 0; j < 6; ++j) {
            const int t = m * 6 + j;
            const float y = (won && j == bj) ? tanhf(sig[t]) : 0.0f;
            const float pv = fmaxf(psi[base + j] * decay[t], y);
            const float fv = fmaxf(phi[base + j] * 0.5f, y);
            psin[base + j] = pv;
            xbn[base + j]  = pv;
            phin[base + j] = fv;
            cmax = fmaxf(cmax, pv);
        }
        lam2[rowM + m] = cmax;
    }
}

// ---------------------------------------------------------------------------
extern "C" void kernel_launch(void* const* d_in, const int* in_sizes, int n_in,
                              void* d_out, int out_size, void* d_ws, size_t ws_size,
                              hipStream_t stream)
{
    const float* x_a   = (const float*)d_in[0];  // [512,2048]
    const float* x_b   = (const float*)d_in[1];  // [512,6000]
    const float* phi   = (const float*)d_in[2];  // [512,6000]
    const float* psi   = (const float*)d_in[3];  // [512,6000]
    const float* W_a   = (const float*)d_in[4];  // [1000,2048]
    const float* W_b   = (const float*)d_in[5];  // [6000,6000]
    const float* W_d   = (const float*)d_in[6];  // [2048,1000]
    const float* b_d   = (const float*)d_in[7];  // [2048]
    const float* decay = (const float*)d_in[8];  // [6000]

    float* out  = (float*)d_out;                       // [512,2048]
    float* xbn  = out + (size_t)512 * 2048;            // [512,6000]
    float* phin = xbn + (size_t)512 * 6000;            // [512,6000]
    float* psin = phin + (size_t)512 * 6000;           // [512,6000]

    float* lam2 = (float*)d_ws;          // [512,1000] (2 MB; ws proven >= this)

    // No split-K (round-4 arithmetic). Staging:
    //  - z_a [512,1000] in out region (512000 <= 1048576), consumed by rowproc
    //    before the decode GEMM overwrites out.
    //  - s_b [512,6000] in xbn region; rowproc stages its row into LDS before
    //    overwriting (proven pattern).
    float* z_a = out;
    float* s_b = xbn;

    dim3 blk(256);
    // z_a = x_a @ W_a^T          [512,1000], K=2048; grid = 16 bx * 8 by
    gemm_mfma_split<false><<<dim3(16 * 8), blk, 0, stream>>>(x_a, W_a, nullptr, z_a, 512, 1000, 2048);
    // s_b = x_b @ W_b^T          [512,6000], K=6000; grid = 94 bx * 8 by
    gemm_mfma_split<false><<<dim3(94 * 8), blk, 0, stream>>>(x_b, W_b, nullptr, s_b, 512, 6000, 6000);
    // masking pipeline
    rowproc_kernel<<<512, blk, 0, stream>>>(z_a, s_b, phi, psi, decay, xbn, phin, psin, lam2);
    // out = lam2 @ W_d^T + b_d   [512,2048], K=1000; grid = 32 bx * 8 by
    gemm_mfma_split<true><<<dim3(32 * 8), blk, 0, stream>>>(lam2, W_d, b_d, out, 512, 2048, 1000);
}